// Round 1
// baseline (22998.596 us; speedup 1.0000x reference)
//
#include <hip/hip_runtime.h>

#define B_ROWS  4096
#define D_DIM   512
#define H_DIM   2048
#define N_STEPS 32
#define EPS_CONV 0.01f
#define LN_EPSF  1e-5f

__device__ __forceinline__ float wave_reduce_sum(float v) {
#pragma unroll
  for (int o = 32; o > 0; o >>= 1) v += __shfl_down(v, o, 64);
  return v;
}

__device__ __forceinline__ float gelu_exact(float v) {
  return 0.5f * v * (1.0f + erff(v * 0.7071067811865476f));
}

// ---------------- LayerNorm: one block per row, 256 thr x 2 elems ----------
__global__ __launch_bounds__(256)
void ln_kernel(const float* __restrict__ in, const float* __restrict__ g,
               const float* __restrict__ b, float* __restrict__ out) {
  const int row = blockIdx.x;
  const int t = threadIdx.x;
  const float2 v = ((const float2*)(in + (size_t)row * D_DIM))[t];
  float s  = v.x + v.y;
  float sq = v.x * v.x + v.y * v.y;
  s  = wave_reduce_sum(s);
  sq = wave_reduce_sum(sq);
  __shared__ float sd1[4], sd2[4], mb[2];
  const int lane = t & 63, wid = t >> 6;
  if (lane == 0) { sd1[wid] = s; sd2[wid] = sq; }
  __syncthreads();
  if (t == 0) {
    float st = sd1[0] + sd1[1] + sd1[2] + sd1[3];
    float qt = sd2[0] + sd2[1] + sd2[2] + sd2[3];
    float mean = st * (1.0f / (float)D_DIM);
    float var  = qt * (1.0f / (float)D_DIM) - mean * mean;
    mb[0] = mean;
    mb[1] = rsqrtf(var + LN_EPSF);
  }
  __syncthreads();
  const float mean = mb[0], rstd = mb[1];
  const float2 gv = ((const float2*)g)[t];
  const float2 bv = ((const float2*)b)[t];
  float2 r;
  r.x = (v.x - mean) * rstd * gv.x + bv.x;
  r.y = (v.y - mean) * rstd * gv.y + bv.y;
  ((float2*)(out + (size_t)row * D_DIM))[t] = r;
}

// ---------------- fp32 tiled GEMM: C = act(A@W + bias) ---------------------
// A: [M,K] row-major, W: [K,N] row-major, C: [M,N]. 256 threads.
// BM x BN block tile, BK=8, 16x16 thread grid, TM x TN per-thread micro-tile.
template <int BM, int BN>
__global__ __launch_bounds__(256)
void gemm_kernel(const float* __restrict__ A, const float* __restrict__ W,
                 const float* __restrict__ bias, float* __restrict__ C,
                 int M, int N, int K, int do_gelu) {
  constexpr int BK = 8;
  constexpr int TM = BM / 16;
  constexpr int TN = BN / 16;
  __shared__ float As[BK][BM];
  __shared__ float Bs[BK][BN];

  const int tid = threadIdx.x;
  const int m0 = blockIdx.x * BM;
  const int n0 = blockIdx.y * BN;
  const int ty = tid >> 4;   // 0..15
  const int tx = tid & 15;   // 0..15

  float acc[TM][TN];
#pragma unroll
  for (int i = 0; i < TM; ++i)
#pragma unroll
    for (int j = 0; j < TN; ++j) acc[i][j] = 0.0f;

  for (int k0 = 0; k0 < K; k0 += BK) {
    // --- stage A tile (BM x BK), transposed into As[k][m] ---
    if constexpr (BM == 128) {
      const int row = tid >> 1;
      const int col = (tid & 1) * 4;
      const float4 a = *(const float4*)(A + (size_t)(m0 + row) * K + k0 + col);
      As[col + 0][row] = a.x;
      As[col + 1][row] = a.y;
      As[col + 2][row] = a.z;
      As[col + 3][row] = a.w;
    } else {  // BM == 64
      const int row = tid >> 2;
      const int col = (tid & 3) * 2;
      const float2 a = *(const float2*)(A + (size_t)(m0 + row) * K + k0 + col);
      As[col + 0][row] = a.x;
      As[col + 1][row] = a.y;
    }
    // --- stage B tile (BK x BN) ---
    {
      const int row = tid >> 5;         // 0..7
      const int col = (tid & 31) * 4;   // 0..124
      const float4 w = *(const float4*)(W + (size_t)(k0 + row) * N + n0 + col);
      *(float4*)(&Bs[row][col]) = w;
    }
    __syncthreads();
#pragma unroll
    for (int kk = 0; kk < BK; ++kk) {
      float a[TM], b[TN];
#pragma unroll
      for (int i = 0; i < TM; i += 4)
        *(float4*)(a + i) = *(const float4*)(&As[kk][ty * TM + i]);
#pragma unroll
      for (int j = 0; j < TN; j += 4)
        *(float4*)(b + j) = *(const float4*)(&Bs[kk][tx * TN + j]);
#pragma unroll
      for (int i = 0; i < TM; ++i)
#pragma unroll
        for (int j = 0; j < TN; ++j) acc[i][j] = fmaf(a[i], b[j], acc[i][j]);
    }
    __syncthreads();
  }

  // --- epilogue: bias (+gelu), vectorized store ---
  float bv[TN];
#pragma unroll
  for (int j = 0; j < TN; ++j) bv[j] = bias[n0 + tx * TN + j];

#pragma unroll
  for (int i = 0; i < TM; ++i) {
    const int r = m0 + ty * TM + i;
#pragma unroll
    for (int j = 0; j < TN; j += 4) {
      float4 v;
      v.x = acc[i][j + 0] + bv[j + 0];
      v.y = acc[i][j + 1] + bv[j + 1];
      v.z = acc[i][j + 2] + bv[j + 2];
      v.w = acc[i][j + 3] + bv[j + 3];
      if (do_gelu) {
        v.x = gelu_exact(v.x);
        v.y = gelu_exact(v.y);
        v.z = gelu_exact(v.z);
        v.w = gelu_exact(v.w);
      }
      *(float4*)(C + (size_t)r * N + n0 + tx * TN + j) = v;
    }
  }
}

// ---------------- update: dist = ||delta||, mask |= dist<eps, z += delta ----
__global__ __launch_bounds__(256)
void update_kernel(float* __restrict__ z, const float* __restrict__ delta,
                   int* __restrict__ mask) {
  const int row = blockIdx.x;
  const int t = threadIdx.x;
  const float2 d = ((const float2*)(delta + (size_t)row * D_DIM))[t];
  float sq = d.x * d.x + d.y * d.y;
  sq = wave_reduce_sum(sq);
  __shared__ float sd[4];
  __shared__ int frozen_sh;
  const int lane = t & 63, wid = t >> 6;
  if (lane == 0) sd[wid] = sq;
  __syncthreads();
  if (t == 0) {
    const float tot = sd[0] + sd[1] + sd[2] + sd[3];
    const float dist = sqrtf(tot);
    const int m = mask[row];
    const int newly = (dist < EPS_CONV) ? 1 : 0;
    if (!m && newly) mask[row] = 1;
    frozen_sh = m | newly;   // mask updated BEFORE the where(), per reference
  }
  __syncthreads();
  if (!frozen_sh) {
    float2* zp = (float2*)(z + (size_t)row * D_DIM);
    float2 zv = zp[t];
    zv.x += d.x;
    zv.y += d.y;
    zp[t] = zv;
  }
}

// ---------------- final: logits = z@clf_w + clf_b; mask -> float -----------
__global__ __launch_bounds__(256)
void final_kernel(const float* __restrict__ z, const float* __restrict__ clf_w,
                  const float* __restrict__ clf_b, const int* __restrict__ mask,
                  float* __restrict__ logits, float* __restrict__ maskf) {
  const int row = blockIdx.x;
  const int t = threadIdx.x;
  const float2 zv = ((const float2*)(z + (size_t)row * D_DIM))[t];
  const float2 wv = ((const float2*)clf_w)[t];
  float s = zv.x * wv.x + zv.y * wv.y;
  s = wave_reduce_sum(s);
  __shared__ float sd[4];
  const int lane = t & 63, wid = t >> 6;
  if (lane == 0) sd[wid] = s;
  __syncthreads();
  if (t == 0) {
    logits[row] = sd[0] + sd[1] + sd[2] + sd[3] + clf_b[0];
    maskf[row] = mask[row] ? 1.0f : 0.0f;
  }
}

// ---------------- init: z <- z_init (in d_out), mask <- 0 ------------------
__global__ void init_kernel(const float* __restrict__ z_init,
                            float* __restrict__ z, int* __restrict__ mask,
                            int n) {
  const int i = blockIdx.x * blockDim.x + threadIdx.x;
  if (i < n) z[i] = z_init[i];
  if (i < B_ROWS) mask[i] = 0;
}

extern "C" void kernel_launch(void* const* d_in, const int* in_sizes, int n_in,
                              void* d_out, int out_size, void* d_ws,
                              size_t ws_size, hipStream_t stream) {
  const float* z_init = (const float*)d_in[0];
  const float* ln1_g  = (const float*)d_in[1];
  const float* ln1_b  = (const float*)d_in[2];
  const float* w1     = (const float*)d_in[3];
  const float* b1     = (const float*)d_in[4];
  const float* w2     = (const float*)d_in[5];
  const float* b2     = (const float*)d_in[6];
  const float* ln2_g  = (const float*)d_in[7];
  const float* ln2_b  = (const float*)d_in[8];
  const float* w3     = (const float*)d_in[9];
  const float* b3     = (const float*)d_in[10];
  const float* w4     = (const float*)d_in[11];
  const float* b4     = (const float*)d_in[12];
  const float* clf_w  = (const float*)d_in[13];
  const float* clf_b  = (const float*)d_in[14];

  float* out    = (float*)d_out;
  float* logits = out;                 // [B]
  float* maskf  = out + B_ROWS;        // [B]
  float* z      = out + 2 * B_ROWS;    // [B,D] lives in d_out directly

  float* ws = (float*)d_ws;
  float* x  = ws;                                   // [B,D] LN output
  float* h  = x + (size_t)B_ROWS * D_DIM;           // [B,H] gelu output
  float* y  = h + (size_t)B_ROWS * H_DIM;           // [B,D] gemm2/gemm4 output
  int*  mask = (int*)(y + (size_t)B_ROWS * D_DIM);  // [B]

  init_kernel<<<(B_ROWS * D_DIM + 255) / 256, 256, 0, stream>>>(
      z_init, z, mask, B_ROWS * D_DIM);

  const dim3 g_up(B_ROWS / 128, H_DIM / 128);   // (32,16) for D->H gemms
  const dim3 g_dn(B_ROWS / 64, D_DIM / 128);    // (64,4)  for H->D gemms

  for (int s = 0; s < N_STEPS; ++s) {
    ln_kernel<<<B_ROWS, 256, 0, stream>>>(z, ln1_g, ln1_b, x);
    gemm_kernel<128, 128><<<g_up, 256, 0, stream>>>(x, w1, b1, h,
                                                    B_ROWS, H_DIM, D_DIM, 1);
    gemm_kernel<64, 128><<<g_dn, 256, 0, stream>>>(h, w2, b2, y,
                                                   B_ROWS, D_DIM, H_DIM, 0);
    ln_kernel<<<B_ROWS, 256, 0, stream>>>(y, ln2_g, ln2_b, x);
    gemm_kernel<128, 128><<<g_up, 256, 0, stream>>>(x, w3, b3, h,
                                                    B_ROWS, H_DIM, D_DIM, 1);
    gemm_kernel<64, 128><<<g_dn, 256, 0, stream>>>(h, w4, b4, y,
                                                   B_ROWS, D_DIM, H_DIM, 0);
    update_kernel<<<B_ROWS, 256, 0, stream>>>(z, y, mask);
  }
  final_kernel<<<B_ROWS, 256, 0, stream>>>(z, clf_w, clf_b, mask, logits, maskf);
}

// Round 2
// 7654.938 us; speedup vs baseline: 3.0044x; 3.0044x over previous
//
#include <hip/hip_runtime.h>

#define B_ROWS  4096
#define D_DIM   512
#define H_DIM   2048
#define N_STEPS 32
#define EPS_CONV 0.01f
#define LN_EPSF  1e-5f

typedef __attribute__((ext_vector_type(4))) float f32x4;
typedef __attribute__((ext_vector_type(8))) _Float16 h16x8;
typedef unsigned short ushort_t;

__device__ __forceinline__ float wave_reduce_sum(float v) {
#pragma unroll
  for (int o = 32; o > 0; o >>= 1) v += __shfl_down(v, o, 64);
  return v;
}

__device__ __forceinline__ float gelu_exact(float v) {
  return 0.5f * v * (1.0f + erff(v * 0.7071067811865476f));
}

__device__ __forceinline__ void async_copy16(void* lds, const void* g) {
  __builtin_amdgcn_global_load_lds(
      (const __attribute__((address_space(1))) unsigned int*)g,
      (__attribute__((address_space(3))) unsigned int*)lds, 16, 0, 0);
}

__device__ __forceinline__ ushort_t h_bits(_Float16 h) {
  union { _Float16 f; ushort_t u; } c; c.f = h; return c.u;
}

// ============ LayerNorm: one block per row, 256 thr x 2 elems ==============
__global__ __launch_bounds__(256)
void ln_kernel(const float* __restrict__ in, const float* __restrict__ g,
               const float* __restrict__ b, float* __restrict__ out) {
  const int row = blockIdx.x;
  const int t = threadIdx.x;
  const float2 v = ((const float2*)(in + (size_t)row * D_DIM))[t];
  float s  = v.x + v.y;
  float sq = v.x * v.x + v.y * v.y;
  s  = wave_reduce_sum(s);
  sq = wave_reduce_sum(sq);
  __shared__ float sd1[4], sd2[4], mb[2];
  const int lane = t & 63, wid = t >> 6;
  if (lane == 0) { sd1[wid] = s; sd2[wid] = sq; }
  __syncthreads();
  if (t == 0) {
    float st = sd1[0] + sd1[1] + sd1[2] + sd1[3];
    float qt = sd2[0] + sd2[1] + sd2[2] + sd2[3];
    float mean = st * (1.0f / (float)D_DIM);
    float var  = qt * (1.0f / (float)D_DIM) - mean * mean;
    mb[0] = mean;
    mb[1] = rsqrtf(var + LN_EPSF);
  }
  __syncthreads();
  const float mean = mb[0], rstd = mb[1];
  const float2 gv = ((const float2*)g)[t];
  const float2 bv = ((const float2*)b)[t];
  float2 r;
  r.x = (v.x - mean) * rstd * gv.x + bv.x;
  r.y = (v.y - mean) * rstd * gv.y + bv.y;
  ((float2*)(out + (size_t)row * D_DIM))[t] = r;
}

// ============ weight transpose + f16 hi/lo split ===========================
// w [K][N] fp32 -> wh, wl [N][K] f16-bits.  wl = f16((w - f32(wh)) * 1024)
__global__ __launch_bounds__(256)
void transpose_split_kernel(const float* __restrict__ w,
                            ushort_t* __restrict__ wh, ushort_t* __restrict__ wl,
                            int K, int N) {
  __shared__ float t[32][33];
  const int tx = threadIdx.x;   // 0..31
  const int ty = threadIdx.y;   // 0..7
  const int n_base = blockIdx.x * 32;
  const int k_base = blockIdx.y * 32;
#pragma unroll
  for (int r = 0; r < 4; ++r)
    t[ty + r * 8][tx] = w[(size_t)(k_base + ty + r * 8) * N + n_base + tx];
  __syncthreads();
#pragma unroll
  for (int r = 0; r < 4; ++r) {
    const int n = n_base + ty + r * 8;
    const int k = k_base + tx;
    const float v = t[tx][ty + r * 8];
    const _Float16 hi = (_Float16)v;
    const _Float16 lo = (_Float16)((v - (float)hi) * 1024.0f);
    wh[(size_t)n * K + k] = h_bits(hi);
    wl[(size_t)n * K + k] = h_bits(lo);
  }
}

// ============ fp16-split-x3 MFMA GEMM ======================================
// C = act(A @ W + bias);  A [M,K] fp32 row-major;  Wh/Wl [N,K] f16 (W^T).
// BM=128 fixed, BK=32, 256 threads = 4 waves in 2x2, wave tile 64 x BN/2.
template <int BN>
__global__ __launch_bounds__(256, 2)
void gemm_f16x3(const float* __restrict__ A, const ushort_t* __restrict__ Wh,
                const ushort_t* __restrict__ Wl, const float* __restrict__ bias,
                float* __restrict__ C, int M, int N, int K, int do_gelu) {
  constexpr int BM = 128, BK = 32;
  constexpr int FN = BN / 32;         // n-frags per wave
  constexpr int WR = (BN * 4) / 256;  // staging rounds for each W buffer

  __shared__ float    As[BM * BK];    // 16KB, swizzled chunks
  __shared__ ushort_t Bh[BN * BK];    // BN*64B, swizzled
  __shared__ ushort_t Bl[BN * BK];

  const int tid = threadIdx.x;
  const int lane = tid & 63;
  const int wid = tid >> 6;
  const int q = lane >> 4;       // quad 0..3
  const int l16 = lane & 15;
  const int wm = wid >> 1;       // 0..1
  const int wn = wid & 1;        // 0..1

  const int m0 = blockIdx.x * BM;
  const int n0 = blockIdx.y * BN;

  f32x4 acc_h[4][FN], acc_m[4][FN];
#pragma unroll
  for (int i = 0; i < 4; ++i)
#pragma unroll
    for (int j = 0; j < FN; ++j) {
      acc_h[i][j] = (f32x4){0.f, 0.f, 0.f, 0.f};
      acc_m[i][j] = (f32x4){0.f, 0.f, 0.f, 0.f};
    }

  // staging address precompute (global element offsets; += k0 each tile)
  int a_goff[4];
#pragma unroll
  for (int r = 0; r < 4; ++r) {
    const int p = r * 256 + tid;            // chunk id, 8 chunks per A-row
    const int am = p >> 3;
    const int ac = ((p & 7) ^ (am & 7)) * 4;  // swizzled float col
    a_goff[r] = (m0 + am) * K + ac;
  }
  int w_goff[WR];
#pragma unroll
  for (int r = 0; r < WR; ++r) {
    const int p = r * 256 + tid;            // chunk id, 4 chunks per W-row
    const int n = p >> 2;
    const int cw = ((p & 3) ^ ((n >> 1) & 3)) * 8;  // swizzled half col
    w_goff[r] = (n0 + n) * K + cw;
  }

  for (int k0 = 0; k0 < K; k0 += BK) {
    // ---- async stage global -> LDS (16B per lane per issue) ----
#pragma unroll
    for (int r = 0; r < 4; ++r)
      async_copy16(&As[(r * 256 + tid) * 4], &A[a_goff[r] + k0]);
#pragma unroll
    for (int r = 0; r < WR; ++r) {
      async_copy16(&Bh[(r * 256 + tid) * 8], &Wh[w_goff[r] + k0]);
      async_copy16(&Bl[(r * 256 + tid) * 8], &Wl[w_goff[r] + k0]);
    }
    __syncthreads();   // drains vmcnt + joins waves

    // ---- A fragments: read fp32, split to f16 hi + scaled lo ----
    h16x8 ah[4], al[4];
#pragma unroll
    for (int i = 0; i < 4; ++i) {
      const int r = wm * 64 + i * 16 + l16;
      const f32x4 f0 = *(const f32x4*)&As[r * 32 + ((2 * q) ^ (r & 7)) * 4];
      const f32x4 f1 = *(const f32x4*)&As[r * 32 + (((2 * q) + 1) ^ (r & 7)) * 4];
      float fa[8];
      fa[0] = f0[0]; fa[1] = f0[1]; fa[2] = f0[2]; fa[3] = f0[3];
      fa[4] = f1[0]; fa[5] = f1[1]; fa[6] = f1[2]; fa[7] = f1[3];
#pragma unroll
      for (int j = 0; j < 8; ++j) {
        const _Float16 hi = (_Float16)fa[j];
        ah[i][j] = hi;
        al[i][j] = (_Float16)((fa[j] - (float)hi) * 1024.0f);
      }
    }
    // ---- B fragments ----
    h16x8 bh[FN], bl[FN];
#pragma unroll
    for (int j = 0; j < FN; ++j) {
      const int n = wn * (BN / 2) + j * 16 + l16;
      const int off = n * 32 + (q ^ ((n >> 1) & 3)) * 8;
      bh[j] = *(const h16x8*)&Bh[off];
      bl[j] = *(const h16x8*)&Bl[off];
    }
    // ---- 3-term MFMA ----
#pragma unroll
    for (int i = 0; i < 4; ++i)
#pragma unroll
      for (int j = 0; j < FN; ++j) {
        acc_h[i][j] = __builtin_amdgcn_mfma_f32_16x16x32_f16(ah[i], bh[j], acc_h[i][j], 0, 0, 0);
        acc_m[i][j] = __builtin_amdgcn_mfma_f32_16x16x32_f16(al[i], bh[j], acc_m[i][j], 0, 0, 0);
        acc_m[i][j] = __builtin_amdgcn_mfma_f32_16x16x32_f16(ah[i], bl[j], acc_m[i][j], 0, 0, 0);
      }
    __syncthreads();   // protect LDS before next stage overwrites
  }

  // ---- epilogue: combine scaled acc, bias, gelu, store ----
#pragma unroll
  for (int i = 0; i < 4; ++i) {
    const int row = m0 + wm * 64 + i * 16 + q * 4;
#pragma unroll
    for (int j = 0; j < FN; ++j) {
      const int col = n0 + wn * (BN / 2) + j * 16 + l16;
      const float bv = bias[col];
#pragma unroll
      for (int r = 0; r < 4; ++r) {
        float v = acc_h[i][j][r] + acc_m[i][j][r] * (1.0f / 1024.0f) + bv;
        if (do_gelu) v = gelu_exact(v);
        C[(size_t)(row + r) * N + col] = v;
      }
    }
  }
}

// ============ fp32 fallback GEMM (round-1) =================================
template <int BM, int BN>
__global__ __launch_bounds__(256)
void gemm_fp32_fallback(const float* __restrict__ A, const float* __restrict__ W,
                        const float* __restrict__ bias, float* __restrict__ C,
                        int M, int N, int K, int do_gelu) {
  constexpr int BK = 8;
  constexpr int TM = BM / 16;
  constexpr int TN = BN / 16;
  __shared__ float As[BK][BM];
  __shared__ float Bs[BK][BN];
  const int tid = threadIdx.x;
  const int m0 = blockIdx.x * BM;
  const int n0 = blockIdx.y * BN;
  const int ty = tid >> 4, tx = tid & 15;
  float acc[TM][TN];
#pragma unroll
  for (int i = 0; i < TM; ++i)
#pragma unroll
    for (int j = 0; j < TN; ++j) acc[i][j] = 0.0f;
  for (int k0 = 0; k0 < K; k0 += BK) {
    if constexpr (BM == 128) {
      const int row = tid >> 1, col = (tid & 1) * 4;
      const float4 a = *(const float4*)(A + (size_t)(m0 + row) * K + k0 + col);
      As[col + 0][row] = a.x; As[col + 1][row] = a.y;
      As[col + 2][row] = a.z; As[col + 3][row] = a.w;
    } else {
      const int row = tid >> 2, col = (tid & 3) * 2;
      const float2 a = *(const float2*)(A + (size_t)(m0 + row) * K + k0 + col);
      As[col + 0][row] = a.x; As[col + 1][row] = a.y;
    }
    {
      const int row = tid >> 5, col = (tid & 31) * 4;
      const float4 w = *(const float4*)(W + (size_t)(k0 + row) * N + n0 + col);
      *(float4*)(&Bs[row][col]) = w;
    }
    __syncthreads();
#pragma unroll
    for (int kk = 0; kk < BK; ++kk) {
      float a[TM], b[TN];
#pragma unroll
      for (int i = 0; i < TM; i += 4)
        *(float4*)(a + i) = *(const float4*)(&As[kk][ty * TM + i]);
#pragma unroll
      for (int j = 0; j < TN; j += 4)
        *(float4*)(b + j) = *(const float4*)(&Bs[kk][tx * TN + j]);
#pragma unroll
      for (int i = 0; i < TM; ++i)
#pragma unroll
        for (int j = 0; j < TN; ++j) acc[i][j] = fmaf(a[i], b[j], acc[i][j]);
    }
    __syncthreads();
  }
  float bv[TN];
#pragma unroll
  for (int j = 0; j < TN; ++j) bv[j] = bias[n0 + tx * TN + j];
#pragma unroll
  for (int i = 0; i < TM; ++i) {
    const int r = m0 + ty * TM + i;
#pragma unroll
    for (int j = 0; j < TN; j += 4) {
      float4 v;
      v.x = acc[i][j + 0] + bv[j + 0]; v.y = acc[i][j + 1] + bv[j + 1];
      v.z = acc[i][j + 2] + bv[j + 2]; v.w = acc[i][j + 3] + bv[j + 3];
      if (do_gelu) {
        v.x = gelu_exact(v.x); v.y = gelu_exact(v.y);
        v.z = gelu_exact(v.z); v.w = gelu_exact(v.w);
      }
      *(float4*)(C + (size_t)r * N + n0 + tx * TN + j) = v;
    }
  }
}

// ============ update / final / init ========================================
__global__ __launch_bounds__(256)
void update_kernel(float* __restrict__ z, const float* __restrict__ delta,
                   int* __restrict__ mask) {
  const int row = blockIdx.x;
  const int t = threadIdx.x;
  const float2 d = ((const float2*)(delta + (size_t)row * D_DIM))[t];
  float sq = d.x * d.x + d.y * d.y;
  sq = wave_reduce_sum(sq);
  __shared__ float sd[4];
  __shared__ int frozen_sh;
  const int lane = t & 63, wid = t >> 6;
  if (lane == 0) sd[wid] = sq;
  __syncthreads();
  if (t == 0) {
    const float dist = sqrtf(sd[0] + sd[1] + sd[2] + sd[3]);
    const int m = mask[row];
    const int newly = (dist < EPS_CONV) ? 1 : 0;
    if (!m && newly) mask[row] = 1;
    frozen_sh = m | newly;
  }
  __syncthreads();
  if (!frozen_sh) {
    float2* zp = (float2*)(z + (size_t)row * D_DIM);
    float2 zv = zp[t];
    zv.x += d.x; zv.y += d.y;
    zp[t] = zv;
  }
}

__global__ __launch_bounds__(256)
void final_kernel(const float* __restrict__ z, const float* __restrict__ clf_w,
                  const float* __restrict__ clf_b, const int* __restrict__ mask,
                  float* __restrict__ logits, float* __restrict__ maskf) {
  const int row = blockIdx.x;
  const int t = threadIdx.x;
  const float2 zv = ((const float2*)(z + (size_t)row * D_DIM))[t];
  const float2 wv = ((const float2*)clf_w)[t];
  float s = zv.x * wv.x + zv.y * wv.y;
  s = wave_reduce_sum(s);
  __shared__ float sd[4];
  const int lane = t & 63, wid = t >> 6;
  if (lane == 0) sd[wid] = s;
  __syncthreads();
  if (t == 0) {
    logits[row] = sd[0] + sd[1] + sd[2] + sd[3] + clf_b[0];
    maskf[row] = mask[row] ? 1.0f : 0.0f;
  }
}

__global__ void init_kernel(const float* __restrict__ z_init,
                            float* __restrict__ z, int* __restrict__ mask,
                            int n) {
  const int i = blockIdx.x * blockDim.x + threadIdx.x;
  if (i < n) z[i] = z_init[i];
  if (i < B_ROWS) mask[i] = 0;
}

// ============ launch =======================================================
extern "C" void kernel_launch(void* const* d_in, const int* in_sizes, int n_in,
                              void* d_out, int out_size, void* d_ws,
                              size_t ws_size, hipStream_t stream) {
  const float* z_init = (const float*)d_in[0];
  const float* ln1_g  = (const float*)d_in[1];
  const float* ln1_b  = (const float*)d_in[2];
  const float* w1     = (const float*)d_in[3];
  const float* b1     = (const float*)d_in[4];
  const float* w2     = (const float*)d_in[5];
  const float* b2     = (const float*)d_in[6];
  const float* ln2_g  = (const float*)d_in[7];
  const float* ln2_b  = (const float*)d_in[8];
  const float* w3     = (const float*)d_in[9];
  const float* b3     = (const float*)d_in[10];
  const float* w4     = (const float*)d_in[11];
  const float* b4     = (const float*)d_in[12];
  const float* clf_w  = (const float*)d_in[13];
  const float* clf_b  = (const float*)d_in[14];

  float* out    = (float*)d_out;
  float* logits = out;
  float* maskf  = out + B_ROWS;
  float* z      = out + 2 * B_ROWS;   // [B,D] in d_out

  const size_t BD = (size_t)B_ROWS * D_DIM;   // 2M elems
  const size_t BH = (size_t)B_ROWS * H_DIM;   // 8M elems
  const size_t WSZ = (size_t)D_DIM * H_DIM;   // 1M elems per weight

  // fast-path workspace layout
  float* x = (float*)d_ws;            // [B,D]
  float* y = x + BD;                  // [B,D]
  float* h = y + BD;                  // [B,H]
  ushort_t* wt = (ushort_t*)(h + BH); // 8 arrays of WSZ f16-bits
  ushort_t* w1h = wt + 0 * WSZ; ushort_t* w1l = wt + 1 * WSZ;
  ushort_t* w2h = wt + 2 * WSZ; ushort_t* w2l = wt + 3 * WSZ;
  ushort_t* w3h = wt + 4 * WSZ; ushort_t* w3l = wt + 5 * WSZ;
  ushort_t* w4h = wt + 6 * WSZ; ushort_t* w4l = wt + 7 * WSZ;
  int* mask = (int*)(wt + 8 * WSZ);
  const size_t need = (2 * BD + BH) * 4 + 8 * WSZ * 2 + B_ROWS * 4 + 256;

  init_kernel<<<(int)((BD + 255) / 256), 256, 0, stream>>>(z_init, z, mask,
                                                           (int)BD);

  if (ws_size >= need) {
    // ---- fast path: fp16-split-x3 MFMA ----
    const dim3 tb(32, 8);
    transpose_split_kernel<<<dim3(H_DIM / 32, D_DIM / 32), tb, 0, stream>>>(w1, w1h, w1l, D_DIM, H_DIM);
    transpose_split_kernel<<<dim3(D_DIM / 32, H_DIM / 32), tb, 0, stream>>>(w2, w2h, w2l, H_DIM, D_DIM);
    transpose_split_kernel<<<dim3(H_DIM / 32, D_DIM / 32), tb, 0, stream>>>(w3, w3h, w3l, D_DIM, H_DIM);
    transpose_split_kernel<<<dim3(D_DIM / 32, H_DIM / 32), tb, 0, stream>>>(w4, w4h, w4l, H_DIM, D_DIM);

    const dim3 g_up(B_ROWS / 128, H_DIM / 128);  // (32,16)=512 blocks
    const dim3 g_dn(B_ROWS / 128, D_DIM / 64);   // (32,8) =256 blocks
    for (int s = 0; s < N_STEPS; ++s) {
      ln_kernel<<<B_ROWS, 256, 0, stream>>>(z, ln1_g, ln1_b, x);
      gemm_f16x3<128><<<g_up, 256, 0, stream>>>(x, w1h, w1l, b1, h,
                                                B_ROWS, H_DIM, D_DIM, 1);
      gemm_f16x3<64><<<g_dn, 256, 0, stream>>>(h, w2h, w2l, b2, y,
                                               B_ROWS, D_DIM, H_DIM, 0);
      ln_kernel<<<B_ROWS, 256, 0, stream>>>(y, ln2_g, ln2_b, x);
      gemm_f16x3<128><<<g_up, 256, 0, stream>>>(x, w3h, w3l, b3, h,
                                                B_ROWS, H_DIM, D_DIM, 1);
      gemm_f16x3<64><<<g_dn, 256, 0, stream>>>(h, w4h, w4l, b4, y,
                                               B_ROWS, D_DIM, H_DIM, 0);
      update_kernel<<<B_ROWS, 256, 0, stream>>>(z, y, mask);
    }
  } else {
    // ---- fallback: round-1 fp32 pipeline (needs 48MB+eps) ----
    int* mask_fb = (int*)(h + BH);  // reuse slot right after h
    mask = mask_fb;
    const dim3 g_up(B_ROWS / 128, H_DIM / 128);
    const dim3 g_dn(B_ROWS / 64, D_DIM / 128);
    for (int s = 0; s < N_STEPS; ++s) {
      ln_kernel<<<B_ROWS, 256, 0, stream>>>(z, ln1_g, ln1_b, x);
      gemm_fp32_fallback<128, 128><<<g_up, 256, 0, stream>>>(x, w1, b1, h, B_ROWS, H_DIM, D_DIM, 1);
      gemm_fp32_fallback<64, 128><<<g_dn, 256, 0, stream>>>(h, w2, b2, y, B_ROWS, D_DIM, H_DIM, 0);
      ln_kernel<<<B_ROWS, 256, 0, stream>>>(y, ln2_g, ln2_b, x);
      gemm_fp32_fallback<128, 128><<<g_up, 256, 0, stream>>>(x, w3, b3, h, B_ROWS, H_DIM, D_DIM, 1);
      gemm_fp32_fallback<64, 128><<<g_dn, 256, 0, stream>>>(h, w4, b4, y, B_ROWS, D_DIM, H_DIM, 0);
      update_kernel<<<B_ROWS, 256, 0, stream>>>(z, y, mask);
    }
  }
  final_kernel<<<B_ROWS, 256, 0, stream>>>(z, clf_w, clf_b, mask, logits, maskf);
}

// Round 3
// 5198.950 us; speedup vs baseline: 4.4237x; 1.4724x over previous
//
#include <hip/hip_runtime.h>

#define B_ROWS  4096
#define D_DIM   512
#define H_DIM   2048
#define N_STEPS 32
#define EPS_CONV 0.01f
#define LN_EPSF  1e-5f

typedef __attribute__((ext_vector_type(4))) float f32x4;
typedef __attribute__((ext_vector_type(8))) _Float16 h16x8;
typedef unsigned short ushort_t;
typedef unsigned int uint32;

__device__ __forceinline__ float wave_reduce_sum(float v) {
#pragma unroll
  for (int o = 32; o > 0; o >>= 1) v += __shfl_down(v, o, 64);
  return v;
}

__device__ __forceinline__ float gelu_exact(float v) {
  return 0.5f * v * (1.0f + erff(v * 0.7071067811865476f));
}

__device__ __forceinline__ void async_copy16(void* lds, const void* g) {
  __builtin_amdgcn_global_load_lds(
      (const __attribute__((address_space(1))) unsigned int*)g,
      (__attribute__((address_space(3))) unsigned int*)lds, 16, 0, 0);
}

__device__ __forceinline__ ushort_t h_bits(_Float16 h) {
  union { _Float16 f; ushort_t u; } c; c.f = h; return c.u;
}

// pack fp32 -> u32 = lo16<<16 | hi16  (hi = f16(v), lo = f16((v-hi)*1024))
__device__ __forceinline__ uint32 pack_split(float v) {
  const _Float16 hi = (_Float16)v;
  const _Float16 lo = (_Float16)((v - (float)hi) * 1024.0f);
  union { _Float16 f[2]; uint32 u; } c;
  c.f[0] = hi; c.f[1] = lo;
  return c.u;
}

// ============ LayerNorm -> packed hi/lo f16 ================================
// in2 may alias outp row-for-row (each thread reads its bytes before writing).
__global__ __launch_bounds__(256)
void ln_pack_kernel(const float* in, const float* in2, const float* g,
                    const float* b, uint32* outp) {
  const int row = blockIdx.x;
  const int t = threadIdx.x;
  float2 v = ((const float2*)(in + (size_t)row * D_DIM))[t];
  if (in2 != nullptr) {
    const float2 w = ((const float2*)(in2 + (size_t)row * D_DIM))[t];
    v.x += w.x; v.y += w.y;
  }
  float s  = v.x + v.y;
  float sq = v.x * v.x + v.y * v.y;
  s  = wave_reduce_sum(s);
  sq = wave_reduce_sum(sq);
  __shared__ float sd1[4], sd2[4], mb[2];
  const int lane = t & 63, wid = t >> 6;
  if (lane == 0) { sd1[wid] = s; sd2[wid] = sq; }
  __syncthreads();
  if (t == 0) {
    float st = sd1[0] + sd1[1] + sd1[2] + sd1[3];
    float qt = sd2[0] + sd2[1] + sd2[2] + sd2[3];
    float mean = st * (1.0f / (float)D_DIM);
    float var  = qt * (1.0f / (float)D_DIM) - mean * mean;
    mb[0] = mean;
    mb[1] = rsqrtf(var + LN_EPSF);
  }
  __syncthreads();
  const float mean = mb[0], rstd = mb[1];
  const float2 gv = ((const float2*)g)[t];
  const float2 bv = ((const float2*)b)[t];
  uint2 o;
  o.x = pack_split((v.x - mean) * rstd * gv.x + bv.x);
  o.y = pack_split((v.y - mean) * rstd * gv.y + bv.y);
  ((uint2*)(outp + (size_t)row * D_DIM))[t] = o;
}

// ============ weight transpose + f16 hi/lo split ===========================
__global__ __launch_bounds__(256)
void transpose_split_kernel(const float* __restrict__ w,
                            ushort_t* __restrict__ wh, ushort_t* __restrict__ wl,
                            int K, int N) {
  __shared__ float t[32][33];
  const int tx = threadIdx.x;   // 0..31
  const int ty = threadIdx.y;   // 0..7
  const int n_base = blockIdx.x * 32;
  const int k_base = blockIdx.y * 32;
#pragma unroll
  for (int r = 0; r < 4; ++r)
    t[ty + r * 8][tx] = w[(size_t)(k_base + ty + r * 8) * N + n_base + tx];
  __syncthreads();
#pragma unroll
  for (int r = 0; r < 4; ++r) {
    const int n = n_base + ty + r * 8;
    const int k = k_base + tx;
    const float v = t[tx][ty + r * 8];
    const _Float16 hi = (_Float16)v;
    const _Float16 lo = (_Float16)((v - (float)hi) * 1024.0f);
    wh[(size_t)n * K + k] = h_bits(hi);
    wl[(size_t)n * K + k] = h_bits(lo);
  }
}

// ============ packed-input f16x3 MFMA GEMM =================================
// A: packed u32 [M][K]; Wh/Wl: f16 [N][K].  BM=128, BK=32, 4 waves 2x2.
// OUT_PACK: C = pack(gelu(acc+bias)) (u32). else: fp32 partial to C0/C1 by
// blockIdx.z (bias added only on z==0).
template <int BN, bool OUT_PACK>
__global__ __launch_bounds__(256, 2)
void gemm_f16x3p(const uint32* __restrict__ Ap, const ushort_t* __restrict__ Wh,
                 const ushort_t* __restrict__ Wl, const float* __restrict__ bias,
                 uint32* __restrict__ Cp, float* __restrict__ C0,
                 float* __restrict__ C1, int M, int N, int K, int kc) {
  constexpr int BM = 128, BK = 32;
  constexpr int FN = BN / 32;
  constexpr int WR = (BN * 4) / 256;

  __shared__ uint32   As[BM * BK];   // 16KB packed
  __shared__ ushort_t Bh[BN * BK];
  __shared__ ushort_t Bl[BN * BK];

  const int tid = threadIdx.x;
  const int lane = tid & 63;
  const int wid = tid >> 6;
  const int q = lane >> 4;
  const int l16 = lane & 15;
  const int wm = wid >> 1;
  const int wn = wid & 1;

  const int m0 = blockIdx.x * BM;
  const int n0 = blockIdx.y * BN;
  const int kz = blockIdx.z * kc;

  f32x4 acc_h[4][FN], acc_m[4][FN];
#pragma unroll
  for (int i = 0; i < 4; ++i)
#pragma unroll
    for (int j = 0; j < FN; ++j) {
      acc_h[i][j] = (f32x4){0.f, 0.f, 0.f, 0.f};
      acc_m[i][j] = (f32x4){0.f, 0.f, 0.f, 0.f};
    }

  int a_goff[4];
#pragma unroll
  for (int r = 0; r < 4; ++r) {
    const int p = r * 256 + tid;              // 16B chunk id, 8 per A-row
    const int am = p >> 3;
    const int ac = ((p & 7) ^ (am & 7)) * 4;  // packed-elem col (swizzled)
    a_goff[r] = (m0 + am) * K + ac;
  }
  int w_goff[WR];
#pragma unroll
  for (int r = 0; r < WR; ++r) {
    const int p = r * 256 + tid;              // 16B chunk id, 4 per W-row
    const int n = p >> 2;
    const int cw = ((p & 3) ^ ((n >> 1) & 3)) * 8;
    w_goff[r] = (n0 + n) * K + cw;
  }

  for (int k0 = kz; k0 < kz + kc; k0 += BK) {
#pragma unroll
    for (int r = 0; r < 4; ++r)
      async_copy16(&As[(r * 256 + tid) * 4], &Ap[a_goff[r] + k0]);
#pragma unroll
    for (int r = 0; r < WR; ++r) {
      async_copy16(&Bh[(r * 256 + tid) * 8], &Wh[w_goff[r] + k0]);
      async_copy16(&Bl[(r * 256 + tid) * 8], &Wl[w_goff[r] + k0]);
    }
    __syncthreads();

    // ---- A fragments: 2x uint4 LDS read + 8 v_perm per (hi,lo) pair ----
    h16x8 ah[4], al[4];
#pragma unroll
    for (int i = 0; i < 4; ++i) {
      const int r = wm * 64 + i * 16 + l16;
      const uint4 c0 = *(const uint4*)&As[r * 32 + (((2 * q) + 0) ^ (r & 7)) * 4];
      const uint4 c1 = *(const uint4*)&As[r * 32 + (((2 * q) + 1) ^ (r & 7)) * 4];
      union { uint32 u[4]; h16x8 h; } hu, lu;
      hu.u[0] = __builtin_amdgcn_perm(c0.y, c0.x, 0x05040100u);
      hu.u[1] = __builtin_amdgcn_perm(c0.w, c0.z, 0x05040100u);
      hu.u[2] = __builtin_amdgcn_perm(c1.y, c1.x, 0x05040100u);
      hu.u[3] = __builtin_amdgcn_perm(c1.w, c1.z, 0x05040100u);
      lu.u[0] = __builtin_amdgcn_perm(c0.y, c0.x, 0x07060302u);
      lu.u[1] = __builtin_amdgcn_perm(c0.w, c0.z, 0x07060302u);
      lu.u[2] = __builtin_amdgcn_perm(c1.y, c1.x, 0x07060302u);
      lu.u[3] = __builtin_amdgcn_perm(c1.w, c1.z, 0x07060302u);
      ah[i] = hu.h; al[i] = lu.h;
    }
    h16x8 bh[FN], bl[FN];
#pragma unroll
    for (int j = 0; j < FN; ++j) {
      const int n = wn * (BN / 2) + j * 16 + l16;
      const int off = n * 32 + (q ^ ((n >> 1) & 3)) * 8;
      bh[j] = *(const h16x8*)&Bh[off];
      bl[j] = *(const h16x8*)&Bl[off];
    }
#pragma unroll
    for (int i = 0; i < 4; ++i)
#pragma unroll
      for (int j = 0; j < FN; ++j) {
        acc_h[i][j] = __builtin_amdgcn_mfma_f32_16x16x32_f16(ah[i], bh[j], acc_h[i][j], 0, 0, 0);
        acc_m[i][j] = __builtin_amdgcn_mfma_f32_16x16x32_f16(al[i], bh[j], acc_m[i][j], 0, 0, 0);
        acc_m[i][j] = __builtin_amdgcn_mfma_f32_16x16x32_f16(ah[i], bl[j], acc_m[i][j], 0, 0, 0);
      }
    __syncthreads();
  }

  // ---- epilogue ----
#pragma unroll
  for (int i = 0; i < 4; ++i) {
    const int row = m0 + wm * 64 + i * 16 + q * 4;
#pragma unroll
    for (int j = 0; j < FN; ++j) {
      const int col = n0 + wn * (BN / 2) + j * 16 + l16;
      if (OUT_PACK) {
        const float bv = bias[col];
#pragma unroll
        for (int r = 0; r < 4; ++r) {
          float v = acc_h[i][j][r] + acc_m[i][j][r] * (1.0f / 1024.0f) + bv;
          Cp[(size_t)(row + r) * N + col] = pack_split(gelu_exact(v));
        }
      } else {
        float* C = (blockIdx.z == 0) ? C0 : C1;
        const float bv = (blockIdx.z == 0) ? bias[col] : 0.0f;
#pragma unroll
        for (int r = 0; r < 4; ++r) {
          C[(size_t)(row + r) * N + col] =
              acc_h[i][j][r] + acc_m[i][j][r] * (1.0f / 1024.0f) + bv;
        }
      }
    }
  }
}

// ============ update: z += (d0+d1) unless converged =========================
__global__ __launch_bounds__(256)
void update_kernel(float* __restrict__ z, const float* __restrict__ d0,
                   const float* __restrict__ d1, int* __restrict__ mask) {
  const int row = blockIdx.x;
  const int t = threadIdx.x;
  float2 d = ((const float2*)(d0 + (size_t)row * D_DIM))[t];
  const float2 e = ((const float2*)(d1 + (size_t)row * D_DIM))[t];
  d.x += e.x; d.y += e.y;
  float sq = d.x * d.x + d.y * d.y;
  sq = wave_reduce_sum(sq);
  __shared__ float sd[4];
  __shared__ int frozen_sh;
  const int lane = t & 63, wid = t >> 6;
  if (lane == 0) sd[wid] = sq;
  __syncthreads();
  if (t == 0) {
    const float dist = sqrtf(sd[0] + sd[1] + sd[2] + sd[3]);
    const int m = mask[row];
    const int newly = (dist < EPS_CONV) ? 1 : 0;
    if (!m && newly) mask[row] = 1;
    frozen_sh = m | newly;
  }
  __syncthreads();
  if (!frozen_sh) {
    float2* zp = (float2*)(z + (size_t)row * D_DIM);
    float2 zv = zp[t];
    zv.x += d.x; zv.y += d.y;
    zp[t] = zv;
  }
}

__global__ __launch_bounds__(256)
void final_kernel(const float* __restrict__ z, const float* __restrict__ clf_w,
                  const float* __restrict__ clf_b, const int* __restrict__ mask,
                  float* __restrict__ logits, float* __restrict__ maskf) {
  const int row = blockIdx.x;
  const int t = threadIdx.x;
  const float2 zv = ((const float2*)(z + (size_t)row * D_DIM))[t];
  const float2 wv = ((const float2*)clf_w)[t];
  float s = zv.x * wv.x + zv.y * wv.y;
  s = wave_reduce_sum(s);
  __shared__ float sd[4];
  const int lane = t & 63, wid = t >> 6;
  if (lane == 0) sd[wid] = s;
  __syncthreads();
  if (t == 0) {
    logits[row] = sd[0] + sd[1] + sd[2] + sd[3] + clf_b[0];
    maskf[row] = mask[row] ? 1.0f : 0.0f;
  }
}

__global__ void init_kernel(const float* __restrict__ z_init,
                            float* __restrict__ z, int* __restrict__ mask,
                            int n) {
  const int i = blockIdx.x * blockDim.x + threadIdx.x;
  if (i < n) z[i] = z_init[i];
  if (i < B_ROWS) mask[i] = 0;
}

// ============ fp32 fallback (round-1, only if ws too small) ================
__global__ __launch_bounds__(256)
void ln_f32_kernel(const float* __restrict__ in, const float* __restrict__ g,
                   const float* __restrict__ b, float* __restrict__ out) {
  const int row = blockIdx.x;
  const int t = threadIdx.x;
  const float2 v = ((const float2*)(in + (size_t)row * D_DIM))[t];
  float s = v.x + v.y, sq = v.x * v.x + v.y * v.y;
  s = wave_reduce_sum(s); sq = wave_reduce_sum(sq);
  __shared__ float sd1[4], sd2[4], mb[2];
  const int lane = t & 63, wid = t >> 6;
  if (lane == 0) { sd1[wid] = s; sd2[wid] = sq; }
  __syncthreads();
  if (t == 0) {
    float st = sd1[0] + sd1[1] + sd1[2] + sd1[3];
    float qt = sd2[0] + sd2[1] + sd2[2] + sd2[3];
    float mean = st / (float)D_DIM;
    float var = qt / (float)D_DIM - mean * mean;
    mb[0] = mean; mb[1] = rsqrtf(var + LN_EPSF);
  }
  __syncthreads();
  const float mean = mb[0], rstd = mb[1];
  const float2 gv = ((const float2*)g)[t];
  const float2 bv = ((const float2*)b)[t];
  float2 r;
  r.x = (v.x - mean) * rstd * gv.x + bv.x;
  r.y = (v.y - mean) * rstd * gv.y + bv.y;
  ((float2*)(out + (size_t)row * D_DIM))[t] = r;
}

__global__ __launch_bounds__(256)
void update_f32_kernel(float* __restrict__ z, const float* __restrict__ delta,
                       int* __restrict__ mask) {
  const int row = blockIdx.x;
  const int t = threadIdx.x;
  const float2 d = ((const float2*)(delta + (size_t)row * D_DIM))[t];
  float sq = d.x * d.x + d.y * d.y;
  sq = wave_reduce_sum(sq);
  __shared__ float sd[4];
  __shared__ int frozen_sh;
  const int lane = t & 63, wid = t >> 6;
  if (lane == 0) sd[wid] = sq;
  __syncthreads();
  if (t == 0) {
    const float dist = sqrtf(sd[0] + sd[1] + sd[2] + sd[3]);
    const int m = mask[row];
    const int newly = (dist < EPS_CONV) ? 1 : 0;
    if (!m && newly) mask[row] = 1;
    frozen_sh = m | newly;
  }
  __syncthreads();
  if (!frozen_sh) {
    float2* zp = (float2*)(z + (size_t)row * D_DIM);
    float2 zv = zp[t];
    zv.x += d.x; zv.y += d.y;
    zp[t] = zv;
  }
}

template <int BM, int BN>
__global__ __launch_bounds__(256)
void gemm_fp32_fallback(const float* __restrict__ A, const float* __restrict__ W,
                        const float* __restrict__ bias, float* __restrict__ C,
                        int M, int N, int K, int do_gelu) {
  constexpr int BK = 8;
  constexpr int TM = BM / 16;
  constexpr int TN = BN / 16;
  __shared__ float As[BK][BM];
  __shared__ float Bs[BK][BN];
  const int tid = threadIdx.x;
  const int m0 = blockIdx.x * BM;
  const int n0 = blockIdx.y * BN;
  const int ty = tid >> 4, tx = tid & 15;
  float acc[TM][TN];
#pragma unroll
  for (int i = 0; i < TM; ++i)
#pragma unroll
    for (int j = 0; j < TN; ++j) acc[i][j] = 0.0f;
  for (int k0 = 0; k0 < K; k0 += BK) {
    if constexpr (BM == 128) {
      const int row = tid >> 1, col = (tid & 1) * 4;
      const float4 a = *(const float4*)(A + (size_t)(m0 + row) * K + k0 + col);
      As[col + 0][row] = a.x; As[col + 1][row] = a.y;
      As[col + 2][row] = a.z; As[col + 3][row] = a.w;
    } else {
      const int row = tid >> 2, col = (tid & 3) * 2;
      const float2 a = *(const float2*)(A + (size_t)(m0 + row) * K + k0 + col);
      As[col + 0][row] = a.x; As[col + 1][row] = a.y;
    }
    {
      const int row = tid >> 5, col = (tid & 31) * 4;
      const float4 w = *(const float4*)(W + (size_t)(k0 + row) * N + n0 + col);
      *(float4*)(&Bs[row][col]) = w;
    }
    __syncthreads();
#pragma unroll
    for (int kk = 0; kk < BK; ++kk) {
      float a[TM], b[TN];
#pragma unroll
      for (int i = 0; i < TM; i += 4)
        *(float4*)(a + i) = *(const float4*)(&As[kk][ty * TM + i]);
#pragma unroll
      for (int j = 0; j < TN; j += 4)
        *(float4*)(b + j) = *(const float4*)(&Bs[kk][tx * TN + j]);
#pragma unroll
      for (int i = 0; i < TM; ++i)
#pragma unroll
        for (int j = 0; j < TN; ++j) acc[i][j] = fmaf(a[i], b[j], acc[i][j]);
    }
    __syncthreads();
  }
  float bv[TN];
#pragma unroll
  for (int j = 0; j < TN; ++j) bv[j] = bias[n0 + tx * TN + j];
#pragma unroll
  for (int i = 0; i < TM; ++i) {
    const int r = m0 + ty * TM + i;
#pragma unroll
    for (int j = 0; j < TN; j += 4) {
      float4 v;
      v.x = acc[i][j + 0] + bv[j + 0]; v.y = acc[i][j + 1] + bv[j + 1];
      v.z = acc[i][j + 2] + bv[j + 2]; v.w = acc[i][j + 3] + bv[j + 3];
      if (do_gelu) {
        v.x = gelu_exact(v.x); v.y = gelu_exact(v.y);
        v.z = gelu_exact(v.z); v.w = gelu_exact(v.w);
      }
      *(float4*)(C + (size_t)r * N + n0 + tx * TN + j) = v;
    }
  }
}

// ============ launch =======================================================
extern "C" void kernel_launch(void* const* d_in, const int* in_sizes, int n_in,
                              void* d_out, int out_size, void* d_ws,
                              size_t ws_size, hipStream_t stream) {
  const float* z_init = (const float*)d_in[0];
  const float* ln1_g  = (const float*)d_in[1];
  const float* ln1_b  = (const float*)d_in[2];
  const float* w1     = (const float*)d_in[3];
  const float* b1     = (const float*)d_in[4];
  const float* w2     = (const float*)d_in[5];
  const float* b2     = (const float*)d_in[6];
  const float* ln2_g  = (const float*)d_in[7];
  const float* ln2_b  = (const float*)d_in[8];
  const float* w3     = (const float*)d_in[9];
  const float* b3     = (const float*)d_in[10];
  const float* w4     = (const float*)d_in[11];
  const float* b4     = (const float*)d_in[12];
  const float* clf_w  = (const float*)d_in[13];
  const float* clf_b  = (const float*)d_in[14];

  float* out    = (float*)d_out;
  float* logits = out;
  float* maskf  = out + B_ROWS;
  float* z      = out + 2 * B_ROWS;   // [B,D] in d_out

  const size_t BD = (size_t)B_ROWS * D_DIM;
  const size_t BH = (size_t)B_ROWS * H_DIM;
  const size_t WSZ = (size_t)D_DIM * H_DIM;

  // layout: xp[BD u32] | hp[BH u32] | y[BD f32] | weights f16 x8 | mask
  uint32* xp = (uint32*)d_ws;
  uint32* hp = xp + BD;
  float*  y  = (float*)(hp + BH);
  ushort_t* wt = (ushort_t*)(y + BD);
  ushort_t* w1h = wt + 0 * WSZ; ushort_t* w1l = wt + 1 * WSZ;
  ushort_t* w2h = wt + 2 * WSZ; ushort_t* w2l = wt + 3 * WSZ;
  ushort_t* w3h = wt + 4 * WSZ; ushort_t* w3l = wt + 5 * WSZ;
  ushort_t* w4h = wt + 6 * WSZ; ushort_t* w4l = wt + 7 * WSZ;
  int* mask = (int*)(wt + 8 * WSZ);
  float* p1 = (float*)xp;   // split-K chunk-1 partial reuses the dead xp slab
  const size_t need = BD * 4 + BH * 4 + BD * 4 + 8 * WSZ * 2 + B_ROWS * 4 + 256;

  init_kernel<<<(int)((BD + 255) / 256), 256, 0, stream>>>(z_init, z, mask,
                                                           (int)BD);

  if (ws_size >= need) {
    const dim3 tb(32, 8);
    transpose_split_kernel<<<dim3(H_DIM / 32, D_DIM / 32), tb, 0, stream>>>(w1, w1h, w1l, D_DIM, H_DIM);
    transpose_split_kernel<<<dim3(D_DIM / 32, H_DIM / 32), tb, 0, stream>>>(w2, w2h, w2l, H_DIM, D_DIM);
    transpose_split_kernel<<<dim3(H_DIM / 32, D_DIM / 32), tb, 0, stream>>>(w3, w3h, w3l, D_DIM, H_DIM);
    transpose_split_kernel<<<dim3(D_DIM / 32, H_DIM / 32), tb, 0, stream>>>(w4, w4h, w4l, H_DIM, D_DIM);

    const dim3 g_up(B_ROWS / 128, H_DIM / 128, 1);   // 512 blocks
    const dim3 g_dn(B_ROWS / 128, D_DIM / 64, 2);    // 512 blocks, split-K=2
    for (int s = 0; s < N_STEPS; ++s) {
      ln_pack_kernel<<<B_ROWS, 256, 0, stream>>>(z, nullptr, ln1_g, ln1_b, xp);
      gemm_f16x3p<128, true><<<g_up, 256, 0, stream>>>(
          xp, w1h, w1l, b1, hp, nullptr, nullptr, B_ROWS, H_DIM, D_DIM, D_DIM);
      gemm_f16x3p<64, false><<<g_dn, 256, 0, stream>>>(
          hp, w2h, w2l, b2, nullptr, y, p1, B_ROWS, D_DIM, H_DIM, H_DIM / 2);
      ln_pack_kernel<<<B_ROWS, 256, 0, stream>>>(y, p1, ln2_g, ln2_b, xp);
      gemm_f16x3p<128, true><<<g_up, 256, 0, stream>>>(
          xp, w3h, w3l, b3, hp, nullptr, nullptr, B_ROWS, H_DIM, D_DIM, D_DIM);
      gemm_f16x3p<64, false><<<g_dn, 256, 0, stream>>>(
          hp, w4h, w4l, b4, nullptr, y, p1, B_ROWS, D_DIM, H_DIM, H_DIM / 2);
      update_kernel<<<B_ROWS, 256, 0, stream>>>(z, y, p1, mask);
    }
  } else {
    // fallback: round-1 fp32 pipeline
    float* x  = (float*)d_ws;
    float* yf = x + BD;
    float* h  = yf + BD;
    int* mask_fb = (int*)(h + BH);
    mask = mask_fb;
    const dim3 g_up(B_ROWS / 128, H_DIM / 128);
    const dim3 g_dn(B_ROWS / 64, D_DIM / 128);
    for (int s = 0; s < N_STEPS; ++s) {
      ln_f32_kernel<<<B_ROWS, 256, 0, stream>>>(z, ln1_g, ln1_b, x);
      gemm_fp32_fallback<128, 128><<<g_up, 256, 0, stream>>>(x, w1, b1, h, B_ROWS, H_DIM, D_DIM, 1);
      gemm_fp32_fallback<64, 128><<<g_dn, 256, 0, stream>>>(h, w2, b2, yf, B_ROWS, D_DIM, H_DIM, 0);
      ln_f32_kernel<<<B_ROWS, 256, 0, stream>>>(yf, ln2_g, ln2_b, x);
      gemm_fp32_fallback<128, 128><<<g_up, 256, 0, stream>>>(x, w3, b3, h, B_ROWS, H_DIM, D_DIM, 1);
      gemm_fp32_fallback<64, 128><<<g_dn, 256, 0, stream>>>(h, w4, b4, yf, B_ROWS, D_DIM, H_DIM, 0);
      update_f32_kernel<<<B_ROWS, 256, 0, stream>>>(z, yf, mask);
    }
  }
  final_kernel<<<B_ROWS, 256, 0, stream>>>(z, clf_w, clf_b, mask, logits, maskf);
}